// Round 17
// baseline (55.902 us; speedup 1.0000x reference)
//
#include <hip/hip_runtime.h>
#include <math.h>

// GptOssTopKRouter on MI355X — round 17: r16 + global_load_lds direct DMA
// staging (no VGPR roundtrip), source-swizzled for conflict-free LDS reads,
// counted-vmcnt pipeline.
//
// r16 (50.2us) staged X via global->reg->ds_write; this replaces it with
// __builtin_amdgcn_global_load_lds width=16: wave w stages rows 4w..4w+3,
// one instruction per row = the row's contiguous 1KB chunk. LDS dest is
// linear (HW: base + lane*16); bank conflicts on the column-wise b128 reads
// are fixed by PRE-SWIZZLING the global source (lane fetches 16B block
// lane^(row&7)); reads XOR the same key -> exactly 8 lanes per 4-bank group
// (optimal, zero excess conflict). vmcnt(4) keeps next-chunk DMAs in flight
// across barriers; raw s_barrier only.
//
// Compute (r7-r16-verified, byte-identical): logits^T = W[32,2880] @ X^T,
// 6 bf16 MFMA passes of 3-term trunc split (hh,mh,lh,hm,mm,hl; logit err
// ~2e-7, tie-safe top-4). 16x16x32 MFMA; W pre-split fragment-packed
// WB[3][96ks][2et][512] (1.18 MB d_ws, L2-resident; tail: ks 88-93 zero,
// 94-95 remapped to k=2816..2879; chunk 11 loads x[2624..2879]).
// Block = 512 thr = 8 waves; wave w = k-step w of each chunk; 2 M-tiles,
// 4 f32x4 accs. Grid 512 -> 2 blocks/CU (64 KB LDS) = 4 waves/SIMD.

#define HIDDEN 2880
#define NE 32
#define TOPK 4
#define TPB 32            // tokens per block
#define CKF 256           // k-floats per chunk per row
#define KS_TOT 96
#define VS (KS_TOT * 2 * 512)   // ver stride in wb: 98304 shorts

typedef __attribute__((ext_vector_type(8))) short bf16x8;
typedef __attribute__((ext_vector_type(4))) float f32x4;
typedef __attribute__((address_space(3))) unsigned int LU;
typedef __attribute__((address_space(1))) const unsigned int GU;

#define MFMA(a, b, c) __builtin_amdgcn_mfma_f32_16x16x32_bf16((a), (b), (c), 0, 0, 0)

// W[32][2880] fp32 -> WB[3 ver][96 ks][2 et][512] bf16, A-frag order:
// (l,j) = split_ver(W[et*16+(l&15)][k]) where
//   ks < 88 : k = ks*32 + (l>>4)*8 + j
//   88..93  : zero (chunk-11 duplicate guard)
//   94,95   : k = 2624 + (ks-88)*32 + (l>>4)*8 + j   (= 2816..2879)
__global__ void wb_kernel(const float* __restrict__ w, unsigned short* __restrict__ wb) {
    int i = blockIdx.x * 256 + threadIdx.x;
    if (i >= 3 * VS) return;
    int j = i & 7;
    int t = i >> 3;
    int l = t & 63;  t >>= 6;
    int et = t & 1;  t >>= 1;
    int ks = t % KS_TOT;
    int ver = t / KS_TOT;
    unsigned short outv = 0;
    int k = -1;
    if (ks < 88)       k = ks * 32 + (l >> 4) * 8 + j;
    else if (ks >= 94) k = 2624 + (ks - 88) * 32 + (l >> 4) * 8 + j;
    if (k >= 0) {
        int e = et * 16 + (l & 15);
        float v = w[e * HIDDEN + k];
        unsigned u = __float_as_uint(v);
        unsigned h = u >> 16;
        float r = v - __uint_as_float(u & 0xffff0000u);          // exact
        unsigned ur = __float_as_uint(r);
        unsigned m = ur >> 16;
        float r2 = r - __uint_as_float(ur & 0xffff0000u);        // exact
        unsigned lo = __float_as_uint(r2) >> 16;
        outv = (unsigned short)(ver == 0 ? h : (ver == 1 ? m : lo));
    }
    wb[i] = outv;
}

// split 8 consecutive fp32 -> 3 bf16x8 (hi, mid, lo), in-register
__device__ __forceinline__ void split24(float4 a, float4 b,
                                        bf16x8& H, bf16x8& M, bf16x8& L) {
    union { bf16x8 v; unsigned u[4]; } h, m, l;
    float f[8] = {a.x, a.y, a.z, a.w, b.x, b.y, b.z, b.w};
    unsigned hh[8], mm[8], ll[8];
#pragma unroll
    for (int i = 0; i < 8; ++i) {
        unsigned u = __float_as_uint(f[i]);
        hh[i] = u >> 16;
        float r = f[i] - __uint_as_float(u & 0xffff0000u);       // exact
        unsigned ur = __float_as_uint(r);
        mm[i] = ur >> 16;
        float r2 = r - __uint_as_float(ur & 0xffff0000u);        // exact
        ll[i] = __float_as_uint(r2) >> 16;
    }
#pragma unroll
    for (int i = 0; i < 4; ++i) {
        h.u[i] = hh[2 * i] | (hh[2 * i + 1] << 16);
        m.u[i] = mm[2 * i] | (mm[2 * i + 1] << 16);
        l.u[i] = ll[2 * i] | (ll[2 * i + 1] << 16);
    }
    H = h.v; M = m.v; L = l.v;
}

__global__ __launch_bounds__(512, 4)
void router_kernel(const float* __restrict__ x,
                   const unsigned short* __restrict__ wb,
                   const float* __restrict__ bias,
                   float* __restrict__ out_scores,
                   float* __restrict__ out_idx)
{
    __shared__ float buf[2][TPB][CKF];    // 64 KB exactly; epilogue overlays

    const int tid  = threadIdx.x;
    const int lane = tid & 63;
    const int w    = tid >> 6;        // k-step within chunk / staging row group
    const int tl   = lane & 15;       // token within M-tile (B-frag col)
    const int kg   = lane >> 4;       // frag k group
    const int tok0 = blockIdx.x * TPB;

    const unsigned short* wk = wb + lane * 8;

    f32x4 acc0 = {0.f, 0.f, 0.f, 0.f};   // mt0, experts 0-15
    f32x4 acc1 = {0.f, 0.f, 0.f, 0.f};   // mt0, experts 16-31
    f32x4 acc2 = {0.f, 0.f, 0.f, 0.f};   // mt1, experts 0-15
    f32x4 acc3 = {0.f, 0.f, 0.f, 0.f};   // mt1, experts 16-31

// stage chunk c into buf[b]: wave w does rows 4w..4w+3, one DMA per row.
// global source pre-swizzled: lane fetches 16B block (lane ^ (row&7));
// LDS dest linear (HW requirement) -> LDS block p holds global block p^(row&7).
#define STAGEC(b, c) do {                                                         \
    const int ko_ = ((c) < 11 ? (c) * CKF : 2624);                                \
    _Pragma("unroll")                                                             \
    for (int i_ = 0; i_ < 4; ++i_) {                                              \
        const int row_ = 4 * w + i_;                                              \
        const float* g_ = x + (size_t)(tok0 + row_) * HIDDEN + ko_               \
                            + ((lane ^ (row_ & 7)) << 2);                         \
        __builtin_amdgcn_global_load_lds((GU*)g_, (LU*)&buf[b][row_][0],          \
                                         16, 0, 0);                               \
    }                                                                             \
} while (0)

#define COMPUTE(b, c) do {                                                        \
    const unsigned short* p_ = wk + (size_t)(8 * (c) + w) * 1024;                 \
    bf16x8 W0 = *(const bf16x8*)(p_);                                             \
    bf16x8 W1 = *(const bf16x8*)(p_ + 512);                                       \
    bf16x8 W2 = *(const bf16x8*)(p_ + VS);                                        \
    bf16x8 W3 = *(const bf16x8*)(p_ + VS + 512);                                  \
    bf16x8 W4 = *(const bf16x8*)(p_ + 2 * VS);                                    \
    bf16x8 W5 = *(const bf16x8*)(p_ + 2 * VS + 512);                              \
    const int K_  = tl & 7;                       /* read-side swizzle key   */   \
    const int j0_ = w * 8 + kg * 2;               /* logical 16B block index */   \
    float4 a0_ = *(const float4*)(&buf[b][tl][(j0_ ^ K_) << 2]);                  \
    float4 a1_ = *(const float4*)(&buf[b][tl][((j0_ + 1) ^ K_) << 2]);            \
    bf16x8 xh_, xm_, xl_;                                                         \
    split24(a0_, a1_, xh_, xm_, xl_);                                             \
    acc0 = MFMA(W0, xh_, acc0);  acc1 = MFMA(W1, xh_, acc1);                      \
    acc0 = MFMA(W2, xh_, acc0);  acc1 = MFMA(W3, xh_, acc1);                      \
    acc0 = MFMA(W4, xh_, acc0);  acc1 = MFMA(W5, xh_, acc1);                      \
    acc0 = MFMA(W0, xm_, acc0);  acc1 = MFMA(W1, xm_, acc1);                      \
    acc0 = MFMA(W2, xm_, acc0);  acc1 = MFMA(W3, xm_, acc1);                      \
    acc0 = MFMA(W0, xl_, acc0);  acc1 = MFMA(W1, xl_, acc1);                      \
    float4 b0_ = *(const float4*)(&buf[b][16 + tl][(j0_ ^ K_) << 2]);             \
    float4 b1_ = *(const float4*)(&buf[b][16 + tl][((j0_ + 1) ^ K_) << 2]);       \
    split24(b0_, b1_, xh_, xm_, xl_);                                             \
    acc2 = MFMA(W0, xh_, acc2);  acc3 = MFMA(W1, xh_, acc3);                      \
    acc2 = MFMA(W2, xh_, acc2);  acc3 = MFMA(W3, xh_, acc3);                      \
    acc2 = MFMA(W4, xh_, acc2);  acc3 = MFMA(W5, xh_, acc3);                      \
    acc2 = MFMA(W0, xm_, acc2);  acc3 = MFMA(W1, xm_, acc3);                      \
    acc2 = MFMA(W2, xm_, acc2);  acc3 = MFMA(W3, xm_, acc3);                      \
    acc2 = MFMA(W0, xl_, acc2);  acc3 = MFMA(W1, xl_, acc3);                      \
} while (0)

    // prologue: chunks 0,1 in flight; wait chunk 0 (vmcnt(4): chunk 1 stays out)
    STAGEC(0, 0);
    STAGEC(1, 1);
    asm volatile("s_waitcnt vmcnt(4)" ::: "memory");
    __builtin_amdgcn_s_barrier();

#pragma unroll 1
    for (int c = 0; c < 12; ++c) {
        COMPUTE(c & 1, c);
        // all waves done reading buf[c&1] before its DMAs restart
        asm volatile("s_waitcnt lgkmcnt(0)" ::: "memory");
        __builtin_amdgcn_s_barrier();
        if (c + 2 < 12) STAGEC(c & 1, c + 2);
        if (c + 1 < 12) {
            // wait chunk c+1's 4 DMAs (older than c+2's 4, which stay in flight)
            if (c + 2 < 12) asm volatile("s_waitcnt vmcnt(4)" ::: "memory");
            else            asm volatile("s_waitcnt vmcnt(0)" ::: "memory");
            __builtin_amdgcn_s_barrier();
        }
    }

#undef STAGEC
#undef COMPUTE

    __syncthreads();                      // safe: no loads outstanding

    // ---- epilogue overlays buf: C/D layout (r7-r16-verified):
    //      col=lane&15=token, row=(lane>>4)*4+j=expert ----
    float* pool = &buf[0][0][0];
#define PART(p, t, e) pool[((p) * TPB + (t)) * 36 + (e)]
    {
        const int eb = kg * 4;
        *(f32x4*)&PART(w, tl, eb)           = acc0;
        *(f32x4*)&PART(w, tl, 16 + eb)      = acc1;
        *(f32x4*)&PART(w, 16 + tl, eb)      = acc2;
        *(f32x4*)&PART(w, 16 + tl, 16 + eb) = acc3;
    }
    __syncthreads();

    float* score = pool + 8 * TPB * 36;   // [32][33]
    if (tid < TPB) {
        float lg[NE];
#pragma unroll
        for (int e = 0; e < NE; ++e) {
            float s = bias[e];
#pragma unroll
            for (int p = 0; p < 8; ++p) s += PART(p, tid, e);
            lg[e] = s;
        }

        float vals[TOPK]; int idxs[TOPK]; unsigned chosen = 0u;
#pragma unroll
        for (int k = 0; k < TOPK; ++k) {
            float m = -INFINITY; int mi = 0;
#pragma unroll
            for (int e = 0; e < NE; ++e) {
                const bool take = (((chosen >> e) & 1u) == 0u) && (lg[e] > m);
                m  = take ? lg[e] : m;
                mi = take ? e : mi;
            }
            vals[k] = m; idxs[k] = mi; chosen |= (1u << (unsigned)mi);
        }
        const float mx = vals[0];
        float p[TOPK]; float sum = 0.f;
#pragma unroll
        for (int k = 0; k < TOPK; ++k) { p[k] = __expf(vals[k] - mx); sum += p[k]; }
        const float inv = 1.0f / sum;
#pragma unroll
        for (int e = 0; e < NE; ++e) {
            float v = 0.f;
#pragma unroll
            for (int k = 0; k < TOPK; ++k) v = (e == idxs[k]) ? p[k] * inv : v;
            score[tid * 33 + e] = v;
        }
        const int t = tok0 + tid;
        float4 iv = make_float4((float)idxs[0], (float)idxs[1], (float)idxs[2], (float)idxs[3]);
        *reinterpret_cast<float4*>(out_idx + (size_t)t * TOPK) = iv;
    }
    __syncthreads();

    // coalesced score store: 1024 floats, 512 threads x float2
    {
        const int f = tid * 2;
        const int t = f >> 5, e = f & 31;
        float2 v = make_float2(score[t * 33 + e], score[t * 33 + e + 1]);
        *reinterpret_cast<float2*>(out_scores + (size_t)blockIdx.x * TPB * NE + f) = v;
    }
#undef PART
}

extern "C" void kernel_launch(void* const* d_in, const int* in_sizes, int n_in,
                              void* d_out, int out_size, void* d_ws, size_t ws_size,
                              hipStream_t stream)
{
    const float* x = (const float*)d_in[0];
    const float* w = (const float*)d_in[1];
    const float* b = (const float*)d_in[2];
    const int T = in_sizes[0] / HIDDEN;            // 16384 tokens

    unsigned short* wbuf = (unsigned short*)d_ws;  // 3*96*2*512 bf16 = 1.18 MB
    float* out        = (float*)d_out;
    float* out_scores = out;                       // [T, 32]
    float* out_idx    = out + (size_t)T * NE;      // [T, 4] as fp32 values

    wb_kernel<<<dim3((3 * VS + 255) / 256), dim3(256), 0, stream>>>(w, wbuf);
    router_kernel<<<dim3(T / TPB), dim3(512), 0, stream>>>(x, wbuf, b, out_scores, out_idx);
}

// Round 18
// 53.682 us; speedup vs baseline: 1.0414x; 1.0414x over previous
//
#include <hip/hip_runtime.h>
#include <math.h>

// GptOssTopKRouter on MI355X — round 18: r16's winning structure (1KB-burst
// reg-roundtrip staging, 2-barrier chunks, counted vmcnt) with 4 independent
// barrier domains per CU: TPB=16, 256-thr blocks, grid 1024 -> 4 blocks/CU.
//
// r17 lesson: global_load_lds (3 barriers/chunk) lost to r16's reg path
// (2 barriers/chunk) — chunk phases are latency-dominated, so sync count
// and cross-block coverage rule. With only 2 blocks/CU, a barrier-stalled
// block has one partner to cover it; 4 blocks at independent phases keep
// the HBM request stream dense (the 7.2 TB/s fill has no barriers at all).
//
// Compute (r7-r17-verified): logits^T = W[32,2880] @ X^T, 6 bf16 MFMA passes
// of 3-term trunc split (hh,mh,lh,hm,mm,hl; logit err ~2e-7, tie-safe top-4).
// 16x16x32 MFMA; W pre-split fragment-packed WB[3][96ks][2et][512] (1.18 MB
// d_ws, L2-resident; tail: ks 88-93 zero, 94-95 remapped to k=2816..2879;
// chunk 11 loads x[2624..2879]). Block = 4 waves; wave w stages rows
// 4w..4w+3 (one instr = one row's contiguous 1KB) and computes k-steps
// {w, w+4} of every chunk. acc = 2 x f32x4 (16 tokens x 32 experts).
// buf[2][16][260] = 33.3 KB -> 4 blocks/CU = 16 waves/CU = 4/SIMD.

#define HIDDEN 2880
#define NE 32
#define TOPK 4
#define TPB 16            // tokens per block
#define CKF 256           // k-floats per chunk per row
#define ROWF 260          // LDS row stride (floats; +4 pad -> 2-way banks)
#define KS_TOT 96
#define VS (KS_TOT * 2 * 512)   // ver stride in wb: 98304 shorts

typedef __attribute__((ext_vector_type(8))) short bf16x8;
typedef __attribute__((ext_vector_type(4))) float f32x4;

#define MFMA(a, b, c) __builtin_amdgcn_mfma_f32_16x16x32_bf16((a), (b), (c), 0, 0, 0)

// W[32][2880] fp32 -> WB[3 ver][96 ks][2 et][512] bf16, A-frag order:
// (l,j) = split_ver(W[et*16+(l&15)][k]) where
//   ks < 88 : k = ks*32 + (l>>4)*8 + j
//   88..93  : zero (chunk-11 duplicate guard)
//   94,95   : k = 2624 + (ks-88)*32 + (l>>4)*8 + j   (= 2816..2879)
__global__ void wb_kernel(const float* __restrict__ w, unsigned short* __restrict__ wb) {
    int i = blockIdx.x * 256 + threadIdx.x;
    if (i >= 3 * VS) return;
    int j = i & 7;
    int t = i >> 3;
    int l = t & 63;  t >>= 6;
    int et = t & 1;  t >>= 1;
    int ks = t % KS_TOT;
    int ver = t / KS_TOT;
    unsigned short outv = 0;
    int k = -1;
    if (ks < 88)       k = ks * 32 + (l >> 4) * 8 + j;
    else if (ks >= 94) k = 2624 + (ks - 88) * 32 + (l >> 4) * 8 + j;
    if (k >= 0) {
        int e = et * 16 + (l & 15);
        float v = w[e * HIDDEN + k];
        unsigned u = __float_as_uint(v);
        unsigned h = u >> 16;
        float r = v - __uint_as_float(u & 0xffff0000u);          // exact
        unsigned ur = __float_as_uint(r);
        unsigned m = ur >> 16;
        float r2 = r - __uint_as_float(ur & 0xffff0000u);        // exact
        unsigned lo = __float_as_uint(r2) >> 16;
        outv = (unsigned short)(ver == 0 ? h : (ver == 1 ? m : lo));
    }
    wb[i] = outv;
}

// split 8 consecutive fp32 -> 3 bf16x8 (hi, mid, lo), in-register
__device__ __forceinline__ void split24(float4 a, float4 b,
                                        bf16x8& H, bf16x8& M, bf16x8& L) {
    union { bf16x8 v; unsigned u[4]; } h, m, l;
    float f[8] = {a.x, a.y, a.z, a.w, b.x, b.y, b.z, b.w};
    unsigned hh[8], mm[8], ll[8];
#pragma unroll
    for (int i = 0; i < 8; ++i) {
        unsigned u = __float_as_uint(f[i]);
        hh[i] = u >> 16;
        float r = f[i] - __uint_as_float(u & 0xffff0000u);       // exact
        unsigned ur = __float_as_uint(r);
        mm[i] = ur >> 16;
        float r2 = r - __uint_as_float(ur & 0xffff0000u);        // exact
        ll[i] = __float_as_uint(r2) >> 16;
    }
#pragma unroll
    for (int i = 0; i < 4; ++i) {
        h.u[i] = hh[2 * i] | (hh[2 * i + 1] << 16);
        m.u[i] = mm[2 * i] | (mm[2 * i + 1] << 16);
        l.u[i] = ll[2 * i] | (ll[2 * i + 1] << 16);
    }
    H = h.v; M = m.v; L = l.v;
}

__global__ __launch_bounds__(256, 4)
void router_kernel(const float* __restrict__ x,
                   const unsigned short* __restrict__ wb,
                   const float* __restrict__ bias,
                   float* __restrict__ out_scores,
                   float* __restrict__ out_idx)
{
    __shared__ float buf[2][TPB][ROWF];   // 33.28 KB; epilogue overlays

    const int tid  = threadIdx.x;
    const int lane = tid & 63;
    const int w    = tid >> 6;        // 0..3: staging row group / k-step pair
    const int tl   = lane & 15;       // token (B-frag col)
    const int kg   = lane >> 4;       // frag k group
    const int tok0 = blockIdx.x * TPB;

    // staging: wave w owns rows 4w..4w+3; one instr = one row's contiguous 1KB
    const float* xsr = x + (size_t)(tok0 + 4 * w) * HIDDEN + lane * 4;
    const unsigned short* wk = wb + lane * 8;

    f32x4 acc0 = {0.f, 0.f, 0.f, 0.f};   // experts 0-15  x token tl
    f32x4 acc1 = {0.f, 0.f, 0.f, 0.f};   // experts 16-31 x token tl

    float4 ga0, ga1, ga2, ga3, gb0, gb1, gb2, gb3;   // named staging regs

#define GLOAD(g0_, g1_, g2_, g3_, c) do {                                         \
    const int ko_ = ((c) < 11 ? (c) * CKF : 2624);                                \
    g0_ = *(const float4*)(xsr + ko_);                                            \
    g1_ = *(const float4*)(xsr + (size_t)HIDDEN + ko_);                           \
    g2_ = *(const float4*)(xsr + (size_t)2 * HIDDEN + ko_);                       \
    g3_ = *(const float4*)(xsr + (size_t)3 * HIDDEN + ko_);                       \
} while (0)

#define SWRITE(b, g0_, g1_, g2_, g3_) do {                                        \
    float* d_ = &buf[b][4 * w][0] + lane * 4;                                     \
    *(float4*)(d_)            = g0_;                                              \
    *(float4*)(d_ + ROWF)     = g1_;                                              \
    *(float4*)(d_ + 2 * ROWF) = g2_;                                              \
    *(float4*)(d_ + 3 * ROWF) = g3_;                                              \
} while (0)

// raw barrier only — __syncthreads would drain vmcnt(0) and kill the pipeline
#define BAR() do {                                                                \
    asm volatile("s_waitcnt lgkmcnt(0)" ::: "memory");                            \
    __builtin_amdgcn_s_barrier();                                                 \
} while (0)

// one k-step s (ks = 8c+s): 6 W dwordx4 + 2 ds_read_b128 + split + 12 MFMA
#define STEPC(b, c, s) do {                                                       \
    const unsigned short* p_ = wk + (size_t)(8 * (c) + (s)) * 1024;               \
    bf16x8 W0 = *(const bf16x8*)(p_);                                             \
    bf16x8 W1 = *(const bf16x8*)(p_ + 512);                                       \
    bf16x8 W2 = *(const bf16x8*)(p_ + VS);                                        \
    bf16x8 W3 = *(const bf16x8*)(p_ + VS + 512);                                  \
    bf16x8 W4 = *(const bf16x8*)(p_ + 2 * VS);                                    \
    bf16x8 W5 = *(const bf16x8*)(p_ + 2 * VS + 512);                              \
    const int xo_ = (s) * 32 + kg * 8;                                            \
    float4 a0_ = *(const float4*)(&buf[b][tl][xo_]);                              \
    float4 a1_ = *(const float4*)(&buf[b][tl][xo_ + 4]);                          \
    bf16x8 xh_, xm_, xl_;                                                         \
    split24(a0_, a1_, xh_, xm_, xl_);                                             \
    acc0 = MFMA(W0, xh_, acc0);  acc1 = MFMA(W1, xh_, acc1);                      \
    acc0 = MFMA(W2, xh_, acc0);  acc1 = MFMA(W3, xh_, acc1);                      \
    acc0 = MFMA(W4, xh_, acc0);  acc1 = MFMA(W5, xh_, acc1);                      \
    acc0 = MFMA(W0, xm_, acc0);  acc1 = MFMA(W1, xm_, acc1);                      \
    acc0 = MFMA(W2, xm_, acc0);  acc1 = MFMA(W3, xm_, acc1);                      \
    acc0 = MFMA(W0, xl_, acc0);  acc1 = MFMA(W1, xl_, acc1);                      \
} while (0)

#define COMPUTE(b, c) do { STEPC(b, c, w); STEPC(b, c, w + 4); } while (0)

    // prologue: buf0 <- chunk0; gb = chunk1; ga = chunk2 (stays in flight)
    GLOAD(ga0, ga1, ga2, ga3, 0);
    GLOAD(gb0, gb1, gb2, gb3, 1);
    SWRITE(0, ga0, ga1, ga2, ga3);        // counted vmcnt: waits ga only
    GLOAD(ga0, ga1, ga2, ga3, 2);
    BAR();

#pragma unroll 1
    for (int i = 0; i < 6; ++i) {
        const int c0 = 2 * i;
        SWRITE(1, gb0, gb1, gb2, gb3);    // chunk c0+1; ga (c0+2) stays in flight
        if (i < 5) GLOAD(gb0, gb1, gb2, gb3, c0 + 3);
        COMPUTE(0, c0);
        BAR();
        if (i < 5) SWRITE(0, ga0, ga1, ga2, ga3);   // chunk c0+2
        if (i < 4) GLOAD(ga0, ga1, ga2, ga3, c0 + 4);
        COMPUTE(1, c0 + 1);
        BAR();
    }

#undef GLOAD
#undef SWRITE
#undef BAR
#undef STEPC
#undef COMPUTE

    __syncthreads();                      // safe: no loads outstanding

    // ---- epilogue overlays buf: C/D layout (r7-r17-verified):
    //      col=lane&15=token, row=(lane>>4)*4+j=expert ----
    float* pool = &buf[0][0][0];
#define PART(p, t, e) pool[((p) * TPB + (t)) * 36 + (e)]
    {
        const int eb = kg * 4;
        *(f32x4*)&PART(w, tl, eb)      = acc0;
        *(f32x4*)&PART(w, tl, 16 + eb) = acc1;
    }
    __syncthreads();

    float* score = pool + 4 * TPB * 36;   // [16][33]
    if (tid < TPB) {
        float lg[NE];
#pragma unroll
        for (int e = 0; e < NE; ++e) {
            float s = bias[e];
#pragma unroll
            for (int p = 0; p < 4; ++p) s += PART(p, tid, e);
            lg[e] = s;
        }

        float vals[TOPK]; int idxs[TOPK]; unsigned chosen = 0u;
#pragma unroll
        for (int k = 0; k < TOPK; ++k) {
            float m = -INFINITY; int mi = 0;
#pragma unroll
            for (int e = 0; e < NE; ++e) {
                const bool take = (((chosen >> e) & 1u) == 0u) && (lg[e] > m);
                m  = take ? lg[e] : m;
                mi = take ? e : mi;
            }
            vals[k] = m; idxs[k] = mi; chosen |= (1u << (unsigned)mi);
        }
        const float mx = vals[0];
        float p[TOPK]; float sum = 0.f;
#pragma unroll
        for (int k = 0; k < TOPK; ++k) { p[k] = __expf(vals[k] - mx); sum += p[k]; }
        const float inv = 1.0f / sum;
#pragma unroll
        for (int e = 0; e < NE; ++e) {
            float v = 0.f;
#pragma unroll
            for (int k = 0; k < TOPK; ++k) v = (e == idxs[k]) ? p[k] * inv : v;
            score[tid * 33 + e] = v;
        }
        const int t = tok0 + tid;
        float4 iv = make_float4((float)idxs[0], (float)idxs[1], (float)idxs[2], (float)idxs[3]);
        *reinterpret_cast<float4*>(out_idx + (size_t)t * TOPK) = iv;
    }
    __syncthreads();

    // coalesced score store: 512 floats, 256 threads x float2
    {
        const int f = tid * 2;
        const int t = f >> 5, e = f & 31;
        float2 v = make_float2(score[t * 33 + e], score[t * 33 + e + 1]);
        *reinterpret_cast<float2*>(out_scores + (size_t)blockIdx.x * TPB * NE + f) = v;
    }
#undef PART
}

extern "C" void kernel_launch(void* const* d_in, const int* in_sizes, int n_in,
                              void* d_out, int out_size, void* d_ws, size_t ws_size,
                              hipStream_t stream)
{
    const float* x = (const float*)d_in[0];
    const float* w = (const float*)d_in[1];
    const float* b = (const float*)d_in[2];
    const int T = in_sizes[0] / HIDDEN;            // 16384 tokens

    unsigned short* wbuf = (unsigned short*)d_ws;  // 3*96*2*512 bf16 = 1.18 MB
    float* out        = (float*)d_out;
    float* out_scores = out;                       // [T, 32]
    float* out_idx    = out + (size_t)T * NE;      // [T, 4] as fp32 values

    wb_kernel<<<dim3((3 * VS + 255) / 256), dim3(256), 0, stream>>>(w, wbuf);
    router_kernel<<<dim3(T / TPB), dim3(256), 0, stream>>>(x, wbuf, b, out_scores, out_idx);
}

// Round 19
// 50.213 us; speedup vs baseline: 1.1133x; 1.0691x over previous
//
#include <hip/hip_runtime.h>
#include <math.h>

// GptOssTopKRouter on MI355X — FINAL (round 16 structure, best measured:
// 50.2 us). 1KB-burst block-cooperative staging with counted-vmcnt pipeline,
// 16x16x32 split-bf16 MFMA compute.
//
// Each global_load_dwordx4 covers ONE token-row's contiguous 1KB (64 lanes x
// 16B). Double-buffered [32][260] tile; SWRITE of chunk c+1 waits
// (compiler-counted) vmcnt on loads issued one full chunk earlier while the
// next chunk's loads remain in flight; ONE raw s_barrier per chunk (never
// __syncthreads in the loop — its vmcnt(0) drain kills the pipeline).
//
// Compute: logits^T = W[32,2880] @ X^T, 6 bf16 MFMA passes of 3-term trunc
// split (hh,mh,lh,hm,mm,hl; logit err ~2e-7, tie-safe top-4 — 2-term split
// flipped a near-tie at T=16384). 16x16x32 MFMA; W pre-split fragment-packed
// WB[3][96ks][2et][512] (1.18 MB d_ws, L2-resident). K tail (2880 = 11.25
// chunks) handled in wb_kernel: chunk 11 loads x[2624..2879]; WB ks 88-93
// zero, ks 94-95 remapped to k=2816..2879 -> no per-lane clamps.
// Block = 512 thr = 8 waves; wave w = k-step w of every chunk (2 M-tiles,
// 4 f32x4 accs). Grid 512 -> 2 blocks/CU = 4 waves/SIMD.
//
// Axis sweep r5-r18: burst 64B/128B/1KB (+4%, saturating); occupancy,
// prefetch depth, MFMA shape: null; global_load_lds DMA: -11% (3rd barrier);
// 1/2/4 blocks-per-CU: 2 best. Delivered X read ~4.3 TB/s = ~70% of the
// 6.3 TB/s copy ceiling; residual = DRAM page efficiency of the inherent
// 16K-interleaved-stream read pattern.

#define HIDDEN 2880
#define NE 32
#define TOPK 4
#define TPB 32            // tokens per block
#define CKF 256           // k-floats per chunk per row
#define NCH 12            // chunks (11 full + remapped tail)
#define ROWF 260          // LDS row stride (floats)
#define KS_TOT 96         // 12 chunks x 8 k32-steps
#define VS (KS_TOT * 2 * 512)   // ver stride in wb: 98304 shorts

typedef __attribute__((ext_vector_type(8))) short bf16x8;
typedef __attribute__((ext_vector_type(4))) float f32x4;

#define MFMA(a, b, c) __builtin_amdgcn_mfma_f32_16x16x32_bf16((a), (b), (c), 0, 0, 0)

// W[32][2880] fp32 -> WB[3 ver][96 ks][2 et][512] bf16, A-frag order:
// (l,j) = split_ver(W[et*16+(l&15)][k]) where
//   ks < 88 : k = ks*32 + (l>>4)*8 + j                  (real)
//   88..93  : zero                                       (chunk-11 dup guard)
//   94,95   : k = 2624 + (ks-88)*32 + (l>>4)*8 + j       (= 2816..2879, real)
__global__ void wb_kernel(const float* __restrict__ w, unsigned short* __restrict__ wb) {
    int i = blockIdx.x * 256 + threadIdx.x;
    if (i >= 3 * VS) return;
    int j = i & 7;
    int t = i >> 3;
    int l = t & 63;  t >>= 6;
    int et = t & 1;  t >>= 1;
    int ks = t % KS_TOT;
    int ver = t / KS_TOT;
    unsigned short outv = 0;
    int k = -1;
    if (ks < 88)       k = ks * 32 + (l >> 4) * 8 + j;
    else if (ks >= 94) k = 2624 + (ks - 88) * 32 + (l >> 4) * 8 + j;
    if (k >= 0) {
        int e = et * 16 + (l & 15);
        float v = w[e * HIDDEN + k];
        unsigned u = __float_as_uint(v);
        unsigned h = u >> 16;
        float r = v - __uint_as_float(u & 0xffff0000u);          // exact
        unsigned ur = __float_as_uint(r);
        unsigned m = ur >> 16;
        float r2 = r - __uint_as_float(ur & 0xffff0000u);        // exact
        unsigned lo = __float_as_uint(r2) >> 16;
        outv = (unsigned short)(ver == 0 ? h : (ver == 1 ? m : lo));
    }
    wb[i] = outv;
}

// split 8 consecutive fp32 -> 3 bf16x8 (hi, mid, lo), in-register
__device__ __forceinline__ void split24(float4 a, float4 b,
                                        bf16x8& H, bf16x8& M, bf16x8& L) {
    union { bf16x8 v; unsigned u[4]; } h, m, l;
    float f[8] = {a.x, a.y, a.z, a.w, b.x, b.y, b.z, b.w};
    unsigned hh[8], mm[8], ll[8];
#pragma unroll
    for (int i = 0; i < 8; ++i) {
        unsigned u = __float_as_uint(f[i]);
        hh[i] = u >> 16;
        float r = f[i] - __uint_as_float(u & 0xffff0000u);       // exact
        unsigned ur = __float_as_uint(r);
        mm[i] = ur >> 16;
        float r2 = r - __uint_as_float(ur & 0xffff0000u);        // exact
        ll[i] = __float_as_uint(r2) >> 16;
    }
#pragma unroll
    for (int i = 0; i < 4; ++i) {
        h.u[i] = hh[2 * i] | (hh[2 * i + 1] << 16);
        m.u[i] = mm[2 * i] | (mm[2 * i + 1] << 16);
        l.u[i] = ll[2 * i] | (ll[2 * i + 1] << 16);
    }
    H = h.v; M = m.v; L = l.v;
}

__global__ __launch_bounds__(512, 4)
void router_kernel(const float* __restrict__ x,
                   const unsigned short* __restrict__ wb,
                   const float* __restrict__ bias,
                   float* __restrict__ out_scores,
                   float* __restrict__ out_idx)
{
    __shared__ float buf[2][TPB][ROWF];   // 66.56 KB; epilogue overlays

    const int tid  = threadIdx.x;
    const int lane = tid & 63;
    const int w    = tid >> 6;        // k-step within chunk, staging row group
    const int tl   = lane & 15;       // token within M-tile (B-frag col)
    const int kg   = lane >> 4;       // frag k group
    const int tok0 = blockIdx.x * TPB;

    // staging: wave w owns rows 4w..4w+3; one instr = one row's contiguous 1KB
    const float* xsr = x + (size_t)(tok0 + 4 * w) * HIDDEN + lane * 4;
    const unsigned short* wk = wb + lane * 8;

    f32x4 acc0 = {0.f, 0.f, 0.f, 0.f};   // mt0, experts 0-15
    f32x4 acc1 = {0.f, 0.f, 0.f, 0.f};   // mt0, experts 16-31
    f32x4 acc2 = {0.f, 0.f, 0.f, 0.f};   // mt1, experts 0-15
    f32x4 acc3 = {0.f, 0.f, 0.f, 0.f};   // mt1, experts 16-31

    float4 ga0, ga1, ga2, ga3, gb0, gb1, gb2, gb3;   // named staging regs

#define GLOAD(g0_, g1_, g2_, g3_, c) do {                                         \
    const int ko_ = ((c) < 11 ? (c) * CKF : 2624);                                \
    g0_ = *(const float4*)(xsr + ko_);                                            \
    g1_ = *(const float4*)(xsr + (size_t)HIDDEN + ko_);                           \
    g2_ = *(const float4*)(xsr + (size_t)2 * HIDDEN + ko_);                       \
    g3_ = *(const float4*)(xsr + (size_t)3 * HIDDEN + ko_);                       \
} while (0)

#define SWRITE(b, g0_, g1_, g2_, g3_) do {                                        \
    float* d_ = &buf[b][4 * w][0] + lane * 4;                                     \
    *(float4*)(d_)            = g0_;                                              \
    *(float4*)(d_ + ROWF)     = g1_;                                              \
    *(float4*)(d_ + 2 * ROWF) = g2_;                                              \
    *(float4*)(d_ + 3 * ROWF) = g3_;                                              \
} while (0)

// raw barrier only — __syncthreads would drain vmcnt(0) and kill the pipeline
#define BAR() do {                                                                \
    asm volatile("s_waitcnt lgkmcnt(0)" ::: "memory");                            \
    __builtin_amdgcn_s_barrier();                                                 \
} while (0)

#define COMPUTE(b, c) do {                                                        \
    const unsigned short* p_ = wk + (size_t)(8 * (c) + w) * 1024;                 \
    bf16x8 W0 = *(const bf16x8*)(p_);                                             \
    bf16x8 W1 = *(const bf16x8*)(p_ + 512);                                       \
    bf16x8 W2 = *(const bf16x8*)(p_ + VS);                                        \
    bf16x8 W3 = *(const bf16x8*)(p_ + VS + 512);                                  \
    bf16x8 W4 = *(const bf16x8*)(p_ + 2 * VS);                                    \
    bf16x8 W5 = *(const bf16x8*)(p_ + 2 * VS + 512);                              \
    const int xo_ = w * 32 + kg * 8;                                              \
    float4 a0_ = *(const float4*)(&buf[b][tl][xo_]);                              \
    float4 a1_ = *(const float4*)(&buf[b][tl][xo_ + 4]);                          \
    bf16x8 xh_, xm_, xl_;                                                         \
    split24(a0_, a1_, xh_, xm_, xl_);                                             \
    acc0 = MFMA(W0, xh_, acc0);  acc1 = MFMA(W1, xh_, acc1);                      \
    acc0 = MFMA(W2, xh_, acc0);  acc1 = MFMA(W3, xh_, acc1);                      \
    acc0 = MFMA(W4, xh_, acc0);  acc1 = MFMA(W5, xh_, acc1);                      \
    acc0 = MFMA(W0, xm_, acc0);  acc1 = MFMA(W1, xm_, acc1);                      \
    acc0 = MFMA(W2, xm_, acc0);  acc1 = MFMA(W3, xm_, acc1);                      \
    acc0 = MFMA(W0, xl_, acc0);  acc1 = MFMA(W1, xl_, acc1);                      \
    float4 b0_ = *(const float4*)(&buf[b][16 + tl][xo_]);                         \
    float4 b1_ = *(const float4*)(&buf[b][16 + tl][xo_ + 4]);                     \
    split24(b0_, b1_, xh_, xm_, xl_);                                             \
    acc2 = MFMA(W0, xh_, acc2);  acc3 = MFMA(W1, xh_, acc3);                      \
    acc2 = MFMA(W2, xh_, acc2);  acc3 = MFMA(W3, xh_, acc3);                      \
    acc2 = MFMA(W4, xh_, acc2);  acc3 = MFMA(W5, xh_, acc3);                      \
    acc2 = MFMA(W0, xm_, acc2);  acc3 = MFMA(W1, xm_, acc3);                      \
    acc2 = MFMA(W2, xm_, acc2);  acc3 = MFMA(W3, xm_, acc3);                      \
    acc2 = MFMA(W0, xl_, acc2);  acc3 = MFMA(W1, xl_, acc3);                      \
} while (0)

    // prologue: buf0 <- chunk0; gb = chunk1; ga = chunk2 (stays in flight)
    GLOAD(ga0, ga1, ga2, ga3, 0);
    GLOAD(gb0, gb1, gb2, gb3, 1);
    SWRITE(0, ga0, ga1, ga2, ga3);        // counted vmcnt: waits ga only
    GLOAD(ga0, ga1, ga2, ga3, 2);
    BAR();

#pragma unroll 1
    for (int i = 0; i < 6; ++i) {
        const int c0 = 2 * i;
        SWRITE(1, gb0, gb1, gb2, gb3);    // chunk c0+1; ga (c0+2) stays in flight
        if (i < 5) GLOAD(gb0, gb1, gb2, gb3, c0 + 3);
        COMPUTE(0, c0);
        BAR();                            // buf1 ready; buf0 reads complete
        if (i < 5) SWRITE(0, ga0, ga1, ga2, ga3);   // chunk c0+2
        if (i < 4) GLOAD(ga0, ga1, ga2, ga3, c0 + 4);
        COMPUTE(1, c0 + 1);
        BAR();                            // buf0 ready; buf1 reads complete
    }

#undef GLOAD
#undef SWRITE
#undef BAR
#undef COMPUTE

    __syncthreads();                      // safe now (no loads outstanding)

    // ---- epilogue overlays buf: C/D layout (r7-r17-verified):
    //      col=lane&15=token, row=(lane>>4)*4+j=expert ----
    float* pool = &buf[0][0][0];
#define PART(p, t, e) pool[((p) * TPB + (t)) * 36 + (e)]
    {
        const int eb = kg * 4;
        *(f32x4*)&PART(w, tl, eb)           = acc0;
        *(f32x4*)&PART(w, tl, 16 + eb)      = acc1;
        *(f32x4*)&PART(w, 16 + tl, eb)      = acc2;
        *(f32x4*)&PART(w, 16 + tl, 16 + eb) = acc3;
    }
    __syncthreads();

    float* score = pool + 8 * TPB * 36;   // [32][33]
    if (tid < TPB) {
        float lg[NE];
#pragma unroll
        for (int e = 0; e < NE; ++e) {
            float s = bias[e];
#pragma unroll
            for (int p = 0; p < 8; ++p) s += PART(p, tid, e);
            lg[e] = s;
        }

        float vals[TOPK]; int idxs[TOPK]; unsigned chosen = 0u;
#pragma unroll
        for (int k = 0; k < TOPK; ++k) {
            float m = -INFINITY; int mi = 0;
#pragma unroll
            for (int e = 0; e < NE; ++e) {
                const bool take = (((chosen >> e) & 1u) == 0u) && (lg[e] > m);
                m  = take ? lg[e] : m;
                mi = take ? e : mi;
            }
            vals[k] = m; idxs[k] = mi; chosen |= (1u << (unsigned)mi);
        }
        const float mx = vals[0];
        float p[TOPK]; float sum = 0.f;
#pragma unroll
        for (int k = 0; k < TOPK; ++k) { p[k] = __expf(vals[k] - mx); sum += p[k]; }
        const float inv = 1.0f / sum;
#pragma unroll
        for (int e = 0; e < NE; ++e) {
            float v = 0.f;
#pragma unroll
            for (int k = 0; k < TOPK; ++k) v = (e == idxs[k]) ? p[k] * inv : v;
            score[tid * 33 + e] = v;
        }
        const int t = tok0 + tid;
        float4 iv = make_float4((float)idxs[0], (float)idxs[1], (float)idxs[2], (float)idxs[3]);
        *reinterpret_cast<float4*>(out_idx + (size_t)t * TOPK) = iv;
    }
    __syncthreads();

    // coalesced score store: 1024 floats, 512 threads x float2
    {
        const int f = tid * 2;
        const int t = f >> 5, e = f & 31;
        float2 v = make_float2(score[t * 33 + e], score[t * 33 + e + 1]);
        *reinterpret_cast<float2*>(out_scores + (size_t)blockIdx.x * TPB * NE + f) = v;
    }
#undef PART
}

extern "C" void kernel_launch(void* const* d_in, const int* in_sizes, int n_in,
                              void* d_out, int out_size, void* d_ws, size_t ws_size,
                              hipStream_t stream)
{
    const float* x = (const float*)d_in[0];
    const float* w = (const float*)d_in[1];
    const float* b = (const float*)d_in[2];
    const int T = in_sizes[0] / HIDDEN;            // 16384 tokens

    unsigned short* wbuf = (unsigned short*)d_ws;  // 3*96*2*512 bf16 = 1.18 MB
    float* out        = (float*)d_out;
    float* out_scores = out;                       // [T, 32]
    float* out_idx    = out + (size_t)T * NE;      // [T, 4] as fp32 values

    wb_kernel<<<dim3((3 * VS + 255) / 256), dim3(256), 0, stream>>>(w, wbuf);
    router_kernel<<<dim3(T / TPB), dim3(512), 0, stream>>>(x, wbuf, b, out_scores, out_idx);
}